// Round 11
// baseline (156.190 us; speedup 1.0000x reference)
//
#include <hip/hip_runtime.h>
#include <stdint.h>

typedef int   int4v   __attribute__((ext_vector_type(4)));
typedef float float4v __attribute__((ext_vector_type(4)));

static constexpr int DIM = 4096;          // N = IN = OUT
static constexpr int BT  = 128;           // block tile (M and N)
static constexpr int BK  = 128;           // K-step bytes (2 MFMA k-steps of K=64)
static constexpr int NKT = DIM / BK;      // 32

// ---------------- quantization kernels (row-major int8 out) ----------------
__global__ __launch_bounds__(256) void quant_act_kernel(
    const float* __restrict__ x, const float* __restrict__ s_ptr,
    const int* __restrict__ zp_ptr, int* __restrict__ out, int n4) {
  const float s  = s_ptr[0];
  const int   zp = zp_ptr[0];
  int idx    = blockIdx.x * blockDim.x + threadIdx.x;
  int stride = gridDim.x * blockDim.x;
  for (int i = idx; i < n4; i += stride) {
    float4v v = reinterpret_cast<const float4v*>(x)[i];
    int packed = 0;
#pragma unroll
    for (int j = 0; j < 4; ++j) {
      int q = (int)rintf(v[j] / s) + zp;
      q = min(max(q, 0), 255);
      q -= zp;
      packed |= (q & 255) << (8 * j);
    }
    out[i] = packed;
  }
}

__global__ __launch_bounds__(256) void quant_wgt_kernel(
    const float* __restrict__ w, const float* __restrict__ ws,
    const int* __restrict__ wzp, int* __restrict__ out, int n4) {
  int idx    = blockIdx.x * blockDim.x + threadIdx.x;
  int stride = gridDim.x * blockDim.x;
  for (int i = idx; i < n4; i += stride) {
    const int row = i >> 10;
    const float s = ws[row];
    const int  zp = wzp[row];
    float4v v = reinterpret_cast<const float4v*>(w)[i];
    int packed = 0;
#pragma unroll
    for (int j = 0; j < 4; ++j) {
      int q = (int)rintf(v[j] / s) + zp;
      q = min(max(q, 0), 255);
      q -= zp;
      packed |= (q & 255) << (8 * j);
    }
    out[i] = packed;
  }
}

// ---- int8 GEMM: R7 geometry (128^2 tile, 8 waves 64x32, 64 KiB dbuf,
//      2 blocks/CU) with FRAGMENT-LINEAR LDS: each global_load_lds stages one
//      1-KB MFMA fragment (per-lane global gather src, linear LDS dest), so
//      every ds_read_b128 is lds_base + lane*16 + imm-offset. Zero swizzle
//      VALU, zero bank conflicts by construction.
// LDS buffer layout: A frags [row16(0..7)][kk(0..1)] at (row16*2+kk)*1024;
// B frags same at +16384. Fragment (row16,kk), lane l holds
// [row16*16 + (l&15)][kt*128 + kk*64 + (l>>4)*16 .. +16].

__global__ __launch_bounds__(512, 4) void gemm_i8_frag(
    const signed char* __restrict__ A, const signed char* __restrict__ B,
    const float* __restrict__ s_act, const float* __restrict__ w_scale,
    const float* __restrict__ bias, float* __restrict__ C) {
  extern __shared__ signed char smem[];  // 2 x (A 16K + B 16K) = 64 KiB

  const int tid  = threadIdx.x;
  const int w    = tid >> 6;            // wave 0..7
  const int lane = tid & 63;
  const int wr = w >> 2, wc = w & 3;    // 2 x 4 wave grid; wave tile 64x32
  const int l15 = lane & 15, lhi = lane >> 4;

  const int tileM = blockIdx.y * BT;
  const int tileN = blockIdx.x * BT;

  // per-lane fragment-gather source bases (kk folded in at call site)
  const size_t aSrc = (size_t)(tileM + w * 16 + l15) * DIM + lhi * 16;
  const size_t bSrc = (size_t)(tileN + w * 16 + l15) * DIM + lhi * 16;

  // wave w stages A frags {2w, 2w+1} (row16 = w, kk = 0,1) and same for B
  auto stage = [&](int t) {
    signed char* dst = smem + (t & 1) * 32768;
    const size_t ka = aSrc + (size_t)t * BK;
    const size_t kb = bSrc + (size_t)t * BK;
    __builtin_amdgcn_global_load_lds(
        (const __attribute__((address_space(1))) void*)(A + ka),
        (__attribute__((address_space(3))) void*)(dst + (2 * w) * 1024), 16, 0, 0);
    __builtin_amdgcn_global_load_lds(
        (const __attribute__((address_space(1))) void*)(A + ka + 64),
        (__attribute__((address_space(3))) void*)(dst + (2 * w + 1) * 1024), 16, 0, 0);
    __builtin_amdgcn_global_load_lds(
        (const __attribute__((address_space(1))) void*)(B + kb),
        (__attribute__((address_space(3))) void*)(dst + 16384 + (2 * w) * 1024), 16, 0, 0);
    __builtin_amdgcn_global_load_lds(
        (const __attribute__((address_space(1))) void*)(B + kb + 64),
        (__attribute__((address_space(3))) void*)(dst + 16384 + (2 * w + 1) * 1024), 16, 0, 0);
  };

  int4v acc[4][2] = {};   // [m][n]
  int4v af[4][2];         // [m][kk]
  int4v bf[2][2];         // [n][kk]

  // ---- prologue: stage tile 0 -> buf0
  stage(0);
  asm volatile("s_waitcnt vmcnt(0)" ::: "memory");
  __builtin_amdgcn_s_barrier();

  for (int kt = 0; kt < NKT; ++kt) {
    const signed char* base = smem + (kt & 1) * 32768 + lane * 16;

    // stage kt+1 into the other buffer (in flight during this tile's compute)
    if (kt + 1 < NKT) stage(kt + 1);

    // fragment reads: single vaddr + immediate fragment offsets
#pragma unroll
    for (int m = 0; m < 4; ++m)
#pragma unroll
      for (int kk = 0; kk < 2; ++kk)
        af[m][kk] = *(const int4v*)(base + ((wr * 4 + m) * 2 + kk) * 1024);
#pragma unroll
    for (int n = 0; n < 2; ++n)
#pragma unroll
      for (int kk = 0; kk < 2; ++kk)
        bf[n][kk] = *(const int4v*)(base + 16384 + ((wc * 2 + n) * 2 + kk) * 1024);

    __builtin_amdgcn_s_setprio(1);
#pragma unroll
    for (int kk = 0; kk < 2; ++kk)
#pragma unroll
      for (int m = 0; m < 4; ++m)
#pragma unroll
        for (int n = 0; n < 2; ++n)
          acc[m][n] = __builtin_amdgcn_mfma_i32_16x16x64_i8(
              af[m][kk], bf[n][kk], acc[m][n], 0, 0, 0);
    __builtin_amdgcn_s_setprio(0);

    asm volatile("s_waitcnt vmcnt(0)" ::: "memory");  // kt+1 landed
    __builtin_amdgcn_s_barrier();                     // all reads consumed; buffers swap
  }

  // ---- epilogue: C/D layout col=lane&15, row=(lane>>4)*4+j
  const float sa = s_act[0];
#pragma unroll
  for (int n = 0; n < 2; ++n) {
    const int col = tileN + wc * 32 + n * 16 + l15;
    const float sc = sa * w_scale[col];
    const float bs = bias[col];
#pragma unroll
    for (int m = 0; m < 4; ++m) {
      const int rbase = tileM + wr * 64 + m * 16 + lhi * 4;
#pragma unroll
      for (int j = 0; j < 4; ++j)
        C[(size_t)(rbase + j) * DIM + col] = (float)acc[m][n][j] * sc + bs;
    }
  }
}

// ---------------- launch ----------------
extern "C" void kernel_launch(void* const* d_in, const int* in_sizes, int n_in,
                              void* d_out, int out_size, void* d_ws, size_t ws_size,
                              hipStream_t stream) {
  const float* x    = (const float*)d_in[0];
  const float* w    = (const float*)d_in[1];
  const float* bias = (const float*)d_in[2];
  const float* a_s  = (const float*)d_in[3];
  const int*   a_zp = (const int*)d_in[4];
  const float* w_s  = (const float*)d_in[5];
  const int*   w_zp = (const int*)d_in[6];
  float* out = (float*)d_out;

  signed char* a8 = (signed char*)d_ws;
  signed char* b8 = a8 + (size_t)DIM * DIM;

  const int n4 = DIM * DIM / 4;
  quant_act_kernel<<<2048, 256, 0, stream>>>(x, a_s, a_zp, (int*)a8, n4);
  quant_wgt_kernel<<<2048, 256, 0, stream>>>(w, w_s, w_zp, (int*)b8, n4);

  (void)hipFuncSetAttribute((const void*)gemm_i8_frag,
                            hipFuncAttributeMaxDynamicSharedMemorySize, 65536);
  dim3 grid(DIM / BT, DIM / BT);  // 32 x 32 = 1024 blocks -> 2 resident/CU
  gemm_i8_frag<<<grid, 512, 65536, stream>>>(a8, b8, a_s, w_s, bias, out);
}

// Round 12
// 117.569 us; speedup vs baseline: 1.3285x; 1.3285x over previous
//
#include <hip/hip_runtime.h>
#include <stdint.h>

typedef int   int4v   __attribute__((ext_vector_type(4)));
typedef int   int16v  __attribute__((ext_vector_type(16)));
typedef float float4v __attribute__((ext_vector_type(4)));

static constexpr int DIM = 4096;          // N = IN = OUT
static constexpr int BT  = 128;           // block tile (M and N)
static constexpr int BK  = 128;           // K-step bytes (4 MFMA k-steps of K=32)
static constexpr int NKT = DIM / BK;      // 32
static constexpr int NR32 = DIM / 32;     // 128

// ---------------- quantization -> MFMA-fragment-linear int8 ----------------
// Fragment f = (row32*NKT + kt)*4 + ks, 1024 B, lane l holds
// src[row32*32 + (l&31)][kt*128 + ks*32 + (l>>5)*16 .. +16]  (verified layout, R6).
// Each wave handles one (row32,kt) pair: reads 32 rows x 128 floats, writes 4 KB
// of contiguous fragments (perfectly coalesced 16 B/lane writes).

__global__ __launch_bounds__(256) void quant_act_frag(
    const float* __restrict__ x, const float* __restrict__ s_ptr,
    const int* __restrict__ zp_ptr, int4v* __restrict__ ap) {
  const float s  = s_ptr[0];
  const int   zp = zp_ptr[0];
  const int wv = threadIdx.x >> 6, lane = threadIdx.x & 63;
  const int l31 = lane & 31, lhalf = lane >> 5;
  const int NP = NR32 * NKT;  // 4096 (row32, kt) pairs
  for (int p = blockIdx.x * 4 + wv; p < NP; p += gridDim.x * 4) {
    const int r32 = p >> 5;          // p / NKT
    const int kt  = p & (NKT - 1);
    const size_t rowoff = (size_t)(r32 * 32 + l31) * DIM + kt * 128 + lhalf * 16;
#pragma unroll
    for (int ks = 0; ks < 4; ++ks) {
      int4v q;
#pragma unroll
      for (int v4 = 0; v4 < 4; ++v4) {
        float4v xv = *reinterpret_cast<const float4v*>(x + rowoff + ks * 32 + v4 * 4);
        int packed = 0;
#pragma unroll
        for (int j = 0; j < 4; ++j) {
          int qq = (int)rintf(xv[j] / s) + zp;
          qq = min(max(qq, 0), 255);
          qq -= zp;
          packed |= (qq & 255) << (8 * j);
        }
        q[v4] = packed;
      }
      ap[((size_t)p * 4 + ks) * 64 + lane] = q;
    }
  }
}

__global__ __launch_bounds__(256) void quant_wgt_frag(
    const float* __restrict__ w, const float* __restrict__ ws,
    const int* __restrict__ wzp, int4v* __restrict__ bp) {
  const int wv = threadIdx.x >> 6, lane = threadIdx.x & 63;
  const int l31 = lane & 31, lhalf = lane >> 5;
  const int NP = NR32 * NKT;
  for (int p = blockIdx.x * 4 + wv; p < NP; p += gridDim.x * 4) {
    const int r32 = p >> 5;
    const int kt  = p & (NKT - 1);
    const int row = r32 * 32 + l31;
    const float s = ws[row];
    const int  zp = wzp[row];
    const size_t rowoff = (size_t)row * DIM + kt * 128 + lhalf * 16;
#pragma unroll
    for (int ks = 0; ks < 4; ++ks) {
      int4v q;
#pragma unroll
      for (int v4 = 0; v4 < 4; ++v4) {
        float4v xv = *reinterpret_cast<const float4v*>(w + rowoff + ks * 32 + v4 * 4);
        int packed = 0;
#pragma unroll
        for (int j = 0; j < 4; ++j) {
          int qq = (int)rintf(xv[j] / s) + zp;
          qq = min(max(qq, 0), 255);
          qq -= zp;
          packed |= (qq & 255) << (8 * j);
        }
        q[v4] = packed;
      }
      bp[((size_t)p * 4 + ks) * 64 + lane] = q;
    }
  }
}

// ---- int8 GEMM: R7 skeleton (128^2 tile, 8 waves, 64 KiB dbuf, 2 blocks/CU)
//      + fragment-linear prepacked operands + mfma_i32_32x32x32_i8.
// Staging: contiguous 1-KB fragments, linear src AND linear LDS dst.
// Reads: ds_read_b128 at (lane*16) + immediate fragment offset — zero swizzle
// VALU, conflict-free by construction. 8 MFMA (K=32) per wave per K-tile.
// LDS buffer: A frags [row32local(0..3)][ks(0..3)] at (r*4+ks)*1024; B at +16384.

__global__ __launch_bounds__(512, 4) void gemm_i8_fraglin(
    const signed char* __restrict__ Ap, const signed char* __restrict__ Bp,
    const float* __restrict__ s_act, const float* __restrict__ w_scale,
    const float* __restrict__ bias, float* __restrict__ C) {
  extern __shared__ signed char smem[];  // 2 x (A 16K + B 16K) = 64 KiB

  const int tid  = threadIdx.x;
  const int w    = tid >> 6;            // wave 0..7
  const int lane = tid & 63;
  const int wr = w >> 2, wc = w & 3;    // 2 x 4 wave grid; wave tile 64x32
  const int l31 = lane & 31, lhalf = lane >> 5;

  const int tileM = blockIdx.y * BT;
  const int tileN = blockIdx.x * BT;

  // staging: waves 0-3 own A fragment group w (row32local = w&3), waves 4-7 own B
  const bool isB = (w >= 4);
  const int  grp = w & 3;                       // row32local
  const signed char* sbase = isB ? Bp : Ap;
  const int r32g = ((isB ? tileN : tileM) >> 5) + grp;
  const int dstoff = (isB ? 16384 : 0) + grp * 4096;

  auto stage = [&](int t) {
    signed char* dst = smem + (t & 1) * 32768 + dstoff;
    const size_t src = (((size_t)r32g * NKT + t) * 4) * 1024 + lane * 16;
#pragma unroll
    for (int i = 0; i < 4; ++i)
      __builtin_amdgcn_global_load_lds(
          (const __attribute__((address_space(1))) void*)(sbase + src + i * 1024),
          (__attribute__((address_space(3))) void*)(dst + i * 1024), 16, 0, 0);
  };

  int16v acc[2] = {};     // [m] 32x32 tiles
  int4v af[2][4];         // [m][ks]
  int4v bf[4];            // [ks]

  // ---- prologue: stage tile 0 -> buf0
  stage(0);
  asm volatile("s_waitcnt vmcnt(0)" ::: "memory");
  __builtin_amdgcn_s_barrier();

  for (int kt = 0; kt < NKT; ++kt) {
    const signed char* base = smem + (kt & 1) * 32768 + lane * 16;

    // stage kt+1 into the other buffer (in flight during this tile's compute)
    if (kt + 1 < NKT) stage(kt + 1);

    // fragment reads: single vaddr + immediate offsets (compiler emits lgkmcnt)
#pragma unroll
    for (int m = 0; m < 2; ++m)
#pragma unroll
      for (int ks = 0; ks < 4; ++ks)
        af[m][ks] = *(const int4v*)(base + ((2 * wr + m) * 4 + ks) * 1024);
#pragma unroll
    for (int ks = 0; ks < 4; ++ks)
      bf[ks] = *(const int4v*)(base + 16384 + (wc * 4 + ks) * 1024);

    __builtin_amdgcn_s_setprio(1);
#pragma unroll
    for (int ks = 0; ks < 4; ++ks)
#pragma unroll
      for (int m = 0; m < 2; ++m)
        acc[m] = __builtin_amdgcn_mfma_i32_32x32x32_i8(af[m][ks], bf[ks], acc[m], 0, 0, 0);
    __builtin_amdgcn_s_setprio(0);

    asm volatile("s_waitcnt vmcnt(0)" ::: "memory");  // kt+1 landed
    __builtin_amdgcn_s_barrier();                     // all reads consumed; swap
  }

  // ---- epilogue: 32x32 C/D layout (R6-verified): col=lane&31,
  //      row = (reg&3) + 8*(reg>>2) + 4*(lane>>5)
  const float sa = s_act[0];
  {
    const int col = tileN + wc * 32 + l31;
    const float sc = sa * w_scale[col];
    const float bs = bias[col];
#pragma unroll
    for (int m = 0; m < 2; ++m) {
      const int rbase = tileM + wr * 64 + m * 32 + 4 * lhalf;
#pragma unroll
      for (int reg = 0; reg < 16; ++reg) {
        const int row = rbase + (reg & 3) + 8 * (reg >> 2);
        C[(size_t)row * DIM + col] = (float)acc[m][reg] * sc + bs;
      }
    }
  }
}

// ---------------- launch ----------------
extern "C" void kernel_launch(void* const* d_in, const int* in_sizes, int n_in,
                              void* d_out, int out_size, void* d_ws, size_t ws_size,
                              hipStream_t stream) {
  const float* x    = (const float*)d_in[0];
  const float* w    = (const float*)d_in[1];
  const float* bias = (const float*)d_in[2];
  const float* a_s  = (const float*)d_in[3];
  const int*   a_zp = (const int*)d_in[4];
  const float* w_s  = (const float*)d_in[5];
  const int*   w_zp = (const int*)d_in[6];
  float* out = (float*)d_out;

  signed char* a8 = (signed char*)d_ws;                 // 16 MB fragment-linear A
  signed char* b8 = a8 + (size_t)DIM * DIM;             // 16 MB fragment-linear B

  quant_act_frag<<<1024, 256, 0, stream>>>(x, a_s, a_zp, (int4v*)a8);
  quant_wgt_frag<<<1024, 256, 0, stream>>>(w, w_s, w_zp, (int4v*)b8);

  (void)hipFuncSetAttribute((const void*)gemm_i8_fraglin,
                            hipFuncAttributeMaxDynamicSharedMemorySize, 65536);
  dim3 grid(DIM / BT, DIM / BT);  // 32 x 32 = 1024 blocks -> 2 resident/CU
  gemm_i8_fraglin<<<grid, 512, 65536, stream>>>(a8, b8, a_s, w_s, bias, out);
}